// Round 9
// baseline (304.222 us; speedup 1.0000x reference)
//
#include <hip/hip_runtime.h>
#include <hip/hip_bf16.h>
#include <math.h>

#define B_    4
#define CIN_  128
#define COUT_ 128
#define H_    128
#define W_    128
#define HW_   (H_*W_)
#define KK_   9

typedef __attribute__((ext_vector_type(8))) short short8;
typedef __attribute__((ext_vector_type(4))) short short4v;
typedef __attribute__((ext_vector_type(4))) float f32x4;
typedef float f2v __attribute__((ext_vector_type(2), aligned(4)));

static __device__ __forceinline__ unsigned f2bf(float f) {
    union { float f; unsigned u; } v; v.f = f;
    return (v.u + 0x7fffu + ((v.u >> 16) & 1u)) >> 16;
}
static __device__ __forceinline__ unsigned pack2bf(float a, float b) {
    union { __hip_bfloat162 h; unsigned u; } v;
    v.h = __float22bfloat162_rn(make_float2(a, b));
    return v.u;
}
static __device__ __forceinline__ float2 bf2f(unsigned u) {
    union { unsigned u; __hip_bfloat162 h; } v; v.u = u;
    return __bfloat1622float2(v.h);
}

// ===========================================================================
// Offset-conv path: VERBATIM R5 (proven)
// ===========================================================================
__global__ __launch_bounds__(256) void woffswz_kernel(
    const float* __restrict__ w_off, unsigned short* __restrict__ woff_swz)
{
    int idx = blockIdx.x * 256 + threadIdx.x;   // [0, 4608)
    int q   = idx >> 7;
    int rem = idx & 127;
    int l   = rem & 63;
    int cbq = q / 9;
    int k   = q - cbq * 9;
    int cb  = (cbq << 5) + ((l >> 4) << 3);
    int oc  = ((rem >> 6) << 4) + (l & 15);
    unsigned r[4];
#pragma unroll
    for (int j = 0; j < 4; ++j) {
        float f0 = 0.f, f1 = 0.f;
        if (oc < 27) {
            f0 = w_off[((size_t)(oc * CIN_ + cb + 2 * j    )) * KK_ + k];
            f1 = w_off[((size_t)(oc * CIN_ + cb + 2 * j + 1)) * KK_ + k];
        }
        r[j] = f2bf(f0) | (f2bf(f1) << 16);
    }
    *(int4*)&woff_swz[(size_t)idx * 8] = make_int4(r[0], r[1], r[2], r[3]);
}

__global__ __launch_bounds__(256) void offset_mfma_kernel(
    const float* __restrict__ feat, const unsigned short* __restrict__ woff_swz,
    const float* __restrict__ b_off, float* __restrict__ offm)
{
    const int tid = threadIdx.x;
    const int bx = blockIdx.x;
    const int lidx = ((bx & 7) << 7) | (bx >> 3);
    const int b  = lidx >> 8;
    const int h  = (lidx & 255) >> 1;
    const int w0 = (lidx & 1) << 6;

    __shared__ unsigned short s_V[64 * 40];

    const int lane = tid & 63;
    const int wave = tid >> 6;
    const int kg = lane >> 4, pn = lane & 15;

    const int bp    = tid & 63;
    const int cgrp8 = (tid >> 6) << 3;

    const float* fbase = feat + (size_t)b * CIN_ * HW_;

    f32x4 acc[2];
    acc[0] = (f32x4){0.f, 0.f, 0.f, 0.f};
    acc[1] = (f32x4){0.f, 0.f, 0.f, 0.f};

    float pf[8];

    auto issue = [&](int qq, float* p) {
        int cbq = qq / 9;
        int k   = qq - cbq * 9;
        int ky = k / 3, kx = k - ky * 3;
        int y = h + ky - 1;
        int x = w0 + bp + kx - 1;
        bool v = ((unsigned)y < (unsigned)H_) & ((unsigned)x < (unsigned)W_);
        const float* g = fbase + (size_t)((cbq << 5) + cgrp8) * HW_ + y * W_ + x;
#pragma unroll
        for (int i = 0; i < 8; ++i) p[i] = v ? g[(size_t)i * HW_] : 0.f;
    };

    issue(0, pf);

    for (int q = 0; q < 36; ++q) {
        unsigned r[4];
#pragma unroll
        for (int i = 0; i < 4; ++i)
            r[i] = f2bf(pf[2 * i]) | (f2bf(pf[2 * i + 1]) << 16);

        const short8* wp = (const short8*)woff_swz + (size_t)(q * 2) * 64 + lane;
        short8 af0 = wp[0];
        short8 af1 = wp[64];

        if (q) __syncthreads();
        *(int4*)&s_V[bp * 40 + cgrp8] = make_int4(r[0], r[1], r[2], r[3]);

        int qn = (q + 1 < 36) ? q + 1 : 35;
        issue(qn, pf);

        __syncthreads();

        short8 bf = *(const short8*)&s_V[(wave * 16 + pn) * 40 + kg * 8];
        acc[0] = __builtin_amdgcn_mfma_f32_16x16x32_bf16(af0, bf, acc[0], 0, 0, 0);
        acc[1] = __builtin_amdgcn_mfma_f32_16x16x32_bf16(af1, bf, acc[1], 0, 0, 0);
    }

    const int row0 = (lane >> 4) << 2;
    const int col  = lane & 15;
    const int pw   = w0 + wave * 16 + col;
#pragma unroll
    for (int mt = 0; mt < 2; ++mt) {
#pragma unroll
        for (int i = 0; i < 4; ++i) {
            int oc = mt * 16 + row0 + i;
            if (oc < 27) {
                float v = acc[mt][i] + b_off[oc];
                if (oc >= 18) v = 1.f / (1.f + __expf(-v));
                offm[((size_t)(b * 27 + oc)) * HW_ + h * W_ + pw] = v;
            }
        }
    }
}

// ===========================================================================
// Prep A: w_dc -> A-fragment order, K=32 chunks — VERBATIM R5 (proven).
// Used by BOTH dcn variants.
// ===========================================================================
__global__ __launch_bounds__(256) void wswz_r5_kernel(
    const float* __restrict__ w_dc, unsigned short* __restrict__ w_swz)
{
    int idx = blockIdx.x * 256 + threadIdx.x;   // [0, 18432)
    int q   = idx >> 9;
    int rem = idx & 511;
    int ocb = rem >> 6;
    int l   = rem & 63;
    int cbq = q / 9;
    int k   = q - cbq * 9;
    int cb  = (cbq << 5) + ((l >> 4) << 3);
    int oc  = (ocb << 4) + (l & 15);
    unsigned r[4];
#pragma unroll
    for (int j = 0; j < 4; ++j) {
        float f0 = w_dc[((size_t)(oc * CIN_ + cb + 2 * j    )) * KK_ + k];
        float f1 = w_dc[((size_t)(oc * CIN_ + cb + 2 * j + 1)) * KK_ + k];
        r[j] = f2bf(f0) | (f2bf(f1) << 16);
    }
    *(int4*)&w_swz[(size_t)idx * 8] = make_int4(r[0], r[1], r[2], r[3]);
}

// ===========================================================================
// NHWC transpose of inp (bf16), 2 batches per launch (b0 = 0 or 2).
// ===========================================================================
__global__ __launch_bounds__(256) void nhwc_kernel(
    const float* __restrict__ inp, unsigned short* __restrict__ inp_t, int b0)
{
    const int bx = blockIdx.x;          // 256 blocks
    const int bl = bx >> 7;             // local batch 0..1
    const int b  = b0 + bl;
    const int h  = bx & 127;
    const float* src = inp + (size_t)b * CIN_ * HW_ + h * W_;
    unsigned short* dst = inp_t + ((size_t)(bl * H_ + h) * W_) * CIN_;
    const int px = threadIdx.x & 127;
    const int cg = threadIdx.x >> 7;
#pragma unroll
    for (int loop = 0; loop < 4; ++loop) {
        int ch = loop * 32 + cg * 16;
        unsigned r[8];
#pragma unroll
        for (int i = 0; i < 8; ++i) {
            float v0 = src[(size_t)(ch + 2 * i    ) * HW_ + px];
            float v1 = src[(size_t)(ch + 2 * i + 1) * HW_ + px];
            r[i] = pack2bf(v0, v1);
        }
        *(int4*)&dst[(size_t)px * CIN_ + ch    ] = make_int4(r[0], r[1], r[2], r[3]);
        *(int4*)&dst[(size_t)px * CIN_ + ch + 8] = make_int4(r[4], r[5], r[6], r[7]);
    }
}

// ===========================================================================
// Kernel 2 (BISECTION): R5 skeleton verbatim — K=32 chunks, R5 w_swz,
// s_V stride 40, two barriers/chunk — with ONLY the gather changed to
// NHWC bf16 4-corner short4 loads (4 channels per 8B load).
// Grid 1024 per launch (2 batches staged), b0 = global batch base.
// ===========================================================================
__global__ __launch_bounds__(256) void dcn_nhwc32_kernel(
    const unsigned short* __restrict__ inp_t, const float* __restrict__ offm,
    const unsigned short* __restrict__ w_swz, const float* __restrict__ b_dc,
    float* __restrict__ out, int b0)
{
    const int tid = threadIdx.x;
    const int bx = blockIdx.x;
    const int lidx = ((bx & 7) << 7) | (bx >> 3);   // 1024 blocks
    const int bl  = lidx >> 9;                      // local batch 0..1
    const int b   = b0 + bl;                        // global batch
    const int h   = (lidx & 511) >> 2;
    const int pw0 = (lidx & 3) << 5;

    __shared__ int4   s_cidx[288];   // 4 corner offsets (pixel*CIN), per tap/px
    __shared__ float4 s_cwgt[288];   // 4 corner weights (validity*mask folded)
    __shared__ unsigned short s_V[32 * 40];

    // 4-corner metadata (R3/R4-proven form), NHWC element offsets
    for (int i = tid; i < 288; i += 256) {
        int k = i >> 5, p = i & 31;
        int ky = k / 3, kx = k - ky * 3;
        int pw = pw0 + p;
        const float* ob = offm + (size_t)b * 27 * HW_ + h * W_ + pw;
        float offy = ob[(2 * k    ) * HW_];
        float offx = ob[(2 * k + 1) * HW_];
        float mask = ob[(18 + k   ) * HW_];
        float py = offy + (float)(h  + ky - 1);
        float px = offx + (float)(pw + kx - 1);
        float y0f = floorf(py), x0f = floorf(px);
        float ly = py - y0f, lx = px - x0f;
        int y0 = (int)y0f, x0 = (int)x0f;
        int y1 = y0 + 1, x1 = x0 + 1;
        bool vy0 = ((unsigned)y0 < (unsigned)H_);
        bool vy1 = ((unsigned)y1 < (unsigned)H_);
        bool vx0 = ((unsigned)x0 < (unsigned)W_);
        bool vx1 = ((unsigned)x1 < (unsigned)W_);
        int cy0 = min(max(y0, 0), H_ - 1), cy1 = min(max(y1, 0), H_ - 1);
        int cx0 = min(max(x0, 0), W_ - 1), cx1 = min(max(x1, 0), W_ - 1);
        s_cidx[i] = make_int4((cy0 * W_ + cx0) * CIN_, (cy0 * W_ + cx1) * CIN_,
                              (cy1 * W_ + cx0) * CIN_, (cy1 * W_ + cx1) * CIN_);
        float w00 = (1.f - ly) * (1.f - lx) * mask;
        float w01 = (1.f - ly) * lx * mask;
        float w10 = ly * (1.f - lx) * mask;
        float w11 = ly * lx * mask;
        if (!(vy0 && vx0)) w00 = 0.f;
        if (!(vy0 && vx1)) w01 = 0.f;
        if (!(vy1 && vx0)) w10 = 0.f;
        if (!(vy1 && vx1)) w11 = 0.f;
        s_cwgt[i] = make_float4(w00, w01, w10, w11);
    }

    const int lane = tid & 63;
    const int wave = tid >> 6;
    const int kg = lane >> 4, pn = lane & 15;
    const int p   = tid & 31;             // staging pixel
    const int cg4 = (tid >> 5) << 2;      // staging channel base (0,4,...,28)

    const unsigned short* gb = inp_t + (size_t)bl * HW_ * CIN_;

    f32x4 acc[2][2];
#pragma unroll
    for (int mt = 0; mt < 2; ++mt)
#pragma unroll
        for (int nt = 0; nt < 2; ++nt) acc[mt][nt] = (f32x4){0.f, 0.f, 0.f, 0.f};

    union S4 { short4v s; unsigned u[2]; };
    S4 pa, pb, pc, pd;
    auto issue = [&](int qq) {
        int cbq = qq / 9;
        int k   = qq - cbq * 9;
        int4 id = s_cidx[(k << 5) + p];
        const unsigned short* base = gb + (cbq << 5) + cg4;
        pa.s = *(const short4v*)(base + id.x);
        pb.s = *(const short4v*)(base + id.y);
        pc.s = *(const short4v*)(base + id.z);
        pd.s = *(const short4v*)(base + id.w);
    };

    __syncthreads();   // metadata visible
    issue(0);

    for (int q = 0; q < 36; ++q) {
        int cbq = q / 9;
        int k   = q - cbq * 9;

        // combine prefetched 4 corners (bf16 -> f32, weights per pixel)
        float4 wt = s_cwgt[(k << 5) + p];
        float2 a0 = bf2f(pa.u[0]), a1 = bf2f(pa.u[1]);
        float2 e0 = bf2f(pb.u[0]), e1 = bf2f(pb.u[1]);
        float2 c0 = bf2f(pc.u[0]), c1 = bf2f(pc.u[1]);
        float2 d0 = bf2f(pd.u[0]), d1 = bf2f(pd.u[1]);
        float v0 = wt.x * a0.x + wt.y * e0.x + wt.z * c0.x + wt.w * d0.x;
        float v1 = wt.x * a0.y + wt.y * e0.y + wt.z * c0.y + wt.w * d0.y;
        float v2 = wt.x * a1.x + wt.y * e1.x + wt.z * c1.x + wt.w * d1.x;
        float v3 = wt.x * a1.y + wt.y * e1.y + wt.z * c1.y + wt.w * d1.y;
        unsigned r0 = f2bf(v0) | (f2bf(v1) << 16);
        unsigned r1 = f2bf(v2) | (f2bf(v3) << 16);

        const short8* wp = (const short8*)w_swz + (size_t)(q * 8 + wave * 2) * 64 + lane;
        short8 af0 = wp[0];
        short8 af1 = wp[64];

        if (q) __syncthreads();
        *(int2*)&s_V[p * 40 + cg4] = make_int2(r0, r1);

        issue(q + 1 < 36 ? q + 1 : 35);

        __syncthreads();

        short8 bf0 = *(const short8*)&s_V[(pn     ) * 40 + kg * 8];
        short8 bf1 = *(const short8*)&s_V[(16 + pn) * 40 + kg * 8];

        acc[0][0] = __builtin_amdgcn_mfma_f32_16x16x32_bf16(af0, bf0, acc[0][0], 0, 0, 0);
        acc[0][1] = __builtin_amdgcn_mfma_f32_16x16x32_bf16(af0, bf1, acc[0][1], 0, 0, 0);
        acc[1][0] = __builtin_amdgcn_mfma_f32_16x16x32_bf16(af1, bf0, acc[1][0], 0, 0, 0);
        acc[1][1] = __builtin_amdgcn_mfma_f32_16x16x32_bf16(af1, bf1, acc[1][1], 0, 0, 0);
    }

    const int row0 = (lane >> 4) << 2;
    const int col  = lane & 15;
#pragma unroll
    for (int mt = 0; mt < 2; ++mt) {
#pragma unroll
        for (int nt = 0; nt < 2; ++nt) {
            int pw = pw0 + nt * 16 + col;
#pragma unroll
            for (int i = 0; i < 4; ++i) {
                int oc = wave * 32 + mt * 16 + row0 + i;
                out[((size_t)(b * COUT_ + oc)) * HW_ + h * W_ + pw] =
                    acc[mt][nt][i] + b_dc[oc];
            }
        }
    }
}

// ===========================================================================
// Fallback: VERBATIM R5 dcn (f32 NCHW paired-corner gather), proven.
// ===========================================================================
__global__ __launch_bounds__(256) void dcn_r5_kernel(
    const float* __restrict__ inp, const float* __restrict__ offm,
    const unsigned short* __restrict__ w_swz, const float* __restrict__ b_dc,
    float* __restrict__ out)
{
    const int tid = threadIdx.x;
    const int bx = blockIdx.x;
    const int lidx = ((bx & 7) << 8) | (bx >> 3);
    const int b   = lidx >> 9;
    const int h   = (lidx & 511) >> 2;
    const int pw0 = (lidx & 3) << 5;

    __shared__ int2   s_midx[288];
    __shared__ float4 s_mwgt[288];
    __shared__ unsigned short s_V[32 * 40];

    for (int i = tid; i < 288; i += 256) {
        int k = i >> 5, p = i & 31;
        int ky = k / 3, kx = k - ky * 3;
        int pw = pw0 + p;
        const float* ob = offm + (size_t)b * 27 * HW_ + h * W_ + pw;
        float offy = ob[(2 * k    ) * HW_];
        float offx = ob[(2 * k + 1) * HW_];
        float mask = ob[(18 + k   ) * HW_];
        float py = offy + (float)(h  + ky - 1);
        float px = offx + (float)(pw + kx - 1);
        float y0f = floorf(py), x0f = floorf(px);
        float ly = py - y0f, lx = px - x0f;
        int y0 = (int)y0f, x0 = (int)x0f;
        int y1 = y0 + 1;
        int hx = min(max(x0, 0), W_ - 2);
        float wlo = 0.f, whi = 0.f;
        if (x0 == hx)          { wlo = 1.f - lx; whi = lx; }
        else if (x0 == hx - 1) { wlo = lx; }
        else if (x0 == hx + 1) { whi = 1.f - lx; }
        float wt_top = ((unsigned)y0 < (unsigned)H_) ? (1.f - ly) * mask : 0.f;
        float wt_bot = ((unsigned)y1 < (unsigned)H_) ? ly * mask : 0.f;
        int cy0 = min(max(y0, 0), H_ - 1), cy1 = min(max(y1, 0), H_ - 1);
        s_midx[i] = make_int2(cy0 * W_ + hx, cy1 * W_ + hx);
        s_mwgt[i] = make_float4(wt_top * wlo, wt_top * whi,
                                wt_bot * wlo, wt_bot * whi);
    }

    const int lane = tid & 63;
    const int wave = tid >> 6;
    const int kg = lane >> 4, pn = lane & 15;
    const int p   = tid & 31;
    const int cg4 = (tid >> 5) << 2;

    const float* gbase = inp + (size_t)b * CIN_ * HW_;

    f32x4 acc[2][2];
#pragma unroll
    for (int mt = 0; mt < 2; ++mt)
#pragma unroll
        for (int nt = 0; nt < 2; ++nt) acc[mt][nt] = (f32x4){0.f, 0.f, 0.f, 0.f};

    f2v pf[8];

    auto issue = [&](int qq, f2v* pfr) {
        int cbq = qq / 9;
        int k   = qq - cbq * 9;
        int2 id = s_midx[(k << 5) + p];
        const float* g = gbase + (size_t)((cbq << 5) + cg4) * HW_;
#pragma unroll
        for (int j = 0; j < 4; ++j) {
            pfr[2 * j]     = *(const f2v*)(g + (size_t)j * HW_ + id.x);
            pfr[2 * j + 1] = *(const f2v*)(g + (size_t)j * HW_ + id.y);
        }
    };

    __syncthreads();
    issue(0, pf);

    for (int q = 0; q < 36; ++q) {
        float4 wt = s_mwgt[((q - (q / 9) * 9) << 5) + p];
        float v[4];
#pragma unroll
        for (int j = 0; j < 4; ++j)
            v[j] = pf[2 * j].x * wt.x + pf[2 * j].y * wt.y
                 + pf[2 * j + 1].x * wt.z + pf[2 * j + 1].y * wt.w;
        unsigned r0 = f2bf(v[0]) | (f2bf(v[1]) << 16);
        unsigned r1 = f2bf(v[2]) | (f2bf(v[3]) << 16);

        const short8* wp = (const short8*)w_swz + (size_t)(q * 8 + wave * 2) * 64 + lane;
        short8 af0 = wp[0];
        short8 af1 = wp[64];

        if (q) __syncthreads();
        *(int2*)&s_V[p * 40 + cg4] = make_int2(r0, r1);

        int qn = (q + 1 < 36) ? q + 1 : 35;
        issue(qn, pf);

        __syncthreads();

        short8 bf0 = *(const short8*)&s_V[(pn     ) * 40 + kg * 8];
        short8 bf1 = *(const short8*)&s_V[(16 + pn) * 40 + kg * 8];

        acc[0][0] = __builtin_amdgcn_mfma_f32_16x16x32_bf16(af0, bf0, acc[0][0], 0, 0, 0);
        acc[0][1] = __builtin_amdgcn_mfma_f32_16x16x32_bf16(af0, bf1, acc[0][1], 0, 0, 0);
        acc[1][0] = __builtin_amdgcn_mfma_f32_16x16x32_bf16(af1, bf0, acc[1][0], 0, 0, 0);
        acc[1][1] = __builtin_amdgcn_mfma_f32_16x16x32_bf16(af1, bf1, acc[1][1], 0, 0, 0);
    }

    const int row0 = (lane >> 4) << 2;
    const int col  = lane & 15;
#pragma unroll
    for (int mt = 0; mt < 2; ++mt) {
#pragma unroll
        for (int nt = 0; nt < 2; ++nt) {
            int pw = pw0 + nt * 16 + col;
#pragma unroll
            for (int i = 0; i < 4; ++i) {
                int oc = wave * 32 + mt * 16 + row0 + i;
                out[((size_t)(b * COUT_ + oc)) * HW_ + h * W_ + pw] =
                    acc[mt][nt][i] + b_dc[oc];
            }
        }
    }
}

// ===========================================================================
// Launch
// ===========================================================================
extern "C" void kernel_launch(void* const* d_in, const int* in_sizes, int n_in,
                              void* d_out, int out_size, void* d_ws, size_t ws_size,
                              hipStream_t stream)
{
    const float* inp   = (const float*)d_in[0];
    const float* feat  = (const float*)d_in[1];
    const float* w_off = (const float*)d_in[2];
    const float* b_off = (const float*)d_in[3];
    const float* w_dc  = (const float*)d_in[4];
    const float* b_dc  = (const float*)d_in[5];
    float* out = (float*)d_out;

    char* ws = (char*)d_ws;
    float*          offm     = (float*)ws;                          // 7,077,888 B
    unsigned short* w_swz    = (unsigned short*)(ws + 7077888);     //   294,912 B
    unsigned short* woff_swz = (unsigned short*)(ws + 7372800);     //    73,728 B
    unsigned short* inp_t    = (unsigned short*)(ws + 7446528);     // 8,388,608 B (2 batches)

    const size_t NEED = 7446528ull + 8388608ull;   // 15,835,136 (known OK per R8)

    woffswz_kernel<<<dim3(18), dim3(256), 0, stream>>>(w_off, woff_swz);
    wswz_r5_kernel<<<dim3(72), dim3(256), 0, stream>>>(w_dc, w_swz);
    offset_mfma_kernel<<<dim3(1024), dim3(256), 0, stream>>>(feat, woff_swz, b_off, offm);

    if (ws_size >= NEED) {
        nhwc_kernel<<<dim3(256), dim3(256), 0, stream>>>(inp, inp_t, 0);
        dcn_nhwc32_kernel<<<dim3(1024), dim3(256), 0, stream>>>(inp_t, offm, w_swz, b_dc, out, 0);
        nhwc_kernel<<<dim3(256), dim3(256), 0, stream>>>(inp, inp_t, 2);
        dcn_nhwc32_kernel<<<dim3(1024), dim3(256), 0, stream>>>(inp_t, offm, w_swz, b_dc, out, 2);
    } else {
        dcn_r5_kernel<<<dim3(2048), dim3(256), 0, stream>>>(inp, offm, w_swz, b_dc, out);
    }
}